// Round 12
// baseline (86.931 us; speedup 1.0000x reference)
//
#include <hip/hip_runtime.h>
#include <hip/hip_bf16.h>

#define NB 4
#define NN 2048
#define NF 256
#define LOG2E 1.4426950408889634f

using bf16x8 = __attribute__((ext_vector_type(8))) short;
using f32x4  = __attribute__((ext_vector_type(4))) float;

__device__ __forceinline__ short f2bf(float f) {
    unsigned u = __float_as_uint(f);
    u += 0x7fffu + ((u >> 16) & 1u);   // RNE, finite inputs only
    return (short)(u >> 16);
}
__device__ __forceinline__ unsigned enc_ord(float f) {
    unsigned u = __float_as_uint(f);
    return (u & 0x80000000u) ? ~u : (u | 0x80000000u);
}
__device__ __forceinline__ float dec_ord(unsigned u) {
    unsigned i = (u & 0x80000000u) ? (u & 0x7fffffffu) : ~u;
    return __uint_as_float(i);
}

// ---- prep: W->W^T bf16, maxfd init (tiny) ----
__global__ __launch_bounds__(256) void prep_kernel(
    const float* __restrict__ W, short* __restrict__ WT, unsigned* __restrict__ maxfd)
{
    const int blk = blockIdx.x, tid = threadIdx.x;
    if (blk < (NF*NF)/256) {
        int t = blk*256 + tid;
        WT[t] = f2bf(W[(t & 255)*NF + (t >> 8)]);   // WT[g][f] = W[f][g]
    } else if (tid < NB) {
        maxfd[tid] = 0u;
    }
}

// ---- h = x@W (bf16 MFMA, K-pipelined) ----
// Writes hTs in gat's wave-step-contiguous layout:
//   hTs[b][fh(2)][t(16)][kt(4)][nt(8)][lane(64)][e(8)]  (bf16)
// so gat reads 8 x 1KB fully-coalesced wave-loads per step. Also fs2/fd2, maxfd.
__global__ __launch_bounds__(256,4) void h_kernel(
    const float* __restrict__ x, const short* __restrict__ WT, const float* __restrict__ a,
    short* __restrict__ hTs, float* __restrict__ fs2, float* __restrict__ fd2,
    unsigned* __restrict__ maxfd)
{
    __shared__ float fs_l[16], fd_l[16];
    const int w  = threadIdx.x >> 6;
    const int l  = threadIdx.x & 63;
    const int lr = l & 15, lg = l >> 4;
    const int b  = blockIdx.x >> 7;
    const int ib = (blockIdx.x & 127) * 16;

    if (threadIdx.x < 16) { fs_l[threadIdx.x] = 0.f; fd_l[threadIdx.x] = 0.f; }
    __syncthreads();

    f32x4 acc[4];
    #pragma unroll
    for (int t = 0; t < 4; t++) acc[t] = (f32x4){0.f,0.f,0.f,0.f};

    const float* xrow = x + (size_t)(b*NN + ib + lr) * NF + 8*lg;
    const short* wtp  = WT + (size_t)(w*64 + lr) * NF + 8*lg;

    float4 xa[2][2]; bf16x8 bfr[2][4];
    xa[0][0] = *(const float4*)(xrow);
    xa[0][1] = *(const float4*)(xrow + 4);
    #pragma unroll
    for (int nt = 0; nt < 4; nt++) bfr[0][nt] = *(const bf16x8*)(wtp + nt*16*NF);

    #pragma unroll
    for (int ks = 0; ks < 8; ks++) {
        const int cur = ks & 1;
        if (ks < 7) {
            const int nxt = cur ^ 1;
            xa[nxt][0] = *(const float4*)(xrow + (ks+1)*32);
            xa[nxt][1] = *(const float4*)(xrow + (ks+1)*32 + 4);
            #pragma unroll
            for (int nt = 0; nt < 4; nt++)
                bfr[nxt][nt] = *(const bf16x8*)(wtp + nt*16*NF + (ks+1)*32);
        }
        bf16x8 af;
        af[0]=f2bf(xa[cur][0].x); af[1]=f2bf(xa[cur][0].y);
        af[2]=f2bf(xa[cur][0].z); af[3]=f2bf(xa[cur][0].w);
        af[4]=f2bf(xa[cur][1].x); af[5]=f2bf(xa[cur][1].y);
        af[6]=f2bf(xa[cur][1].z); af[7]=f2bf(xa[cur][1].w);
        #pragma unroll
        for (int nt = 0; nt < 4; nt++)
            acc[nt] = __builtin_amdgcn_mfma_f32_16x16x32_bf16(af, bfr[cur][nt], acc[nt], 0, 0, 0);
    }

    // store: j = ib + lg*4 + r (4 consecutive), f = w*64 + nt4*16 + lr
    const int t16  = ib >> 7;                    // step index
    const int j7   = (ib & 127) + lg*4;
    const int ktj  = j7 >> 5;
    const int lgs  = (j7 >> 3) & 3;
    const int e0   = j7 & 7;                     // 0 or 4
    const int lane = lgs*16 + lr;

    float fsv[4] = {0,0,0,0}, fdv[4] = {0,0,0,0};
    #pragma unroll
    for (int nt4 = 0; nt4 < 4; nt4++) {
        int g = w*64 + nt4*16 + lr;
        int fh = g >> 7;
        int nt = (g & 127) >> 4;
        float as = a[g], ad = a[NF + g];
        short4 hv;
        hv.x = f2bf(acc[nt4][0]); hv.y = f2bf(acc[nt4][1]);
        hv.z = f2bf(acc[nt4][2]); hv.w = f2bf(acc[nt4][3]);
        size_t idx = (((((size_t)(b*2 + fh)*16 + t16)*4 + ktj)*8 + nt)*64 + lane)*8 + e0;
        *(short4*)(hTs + idx) = hv;
        #pragma unroll
        for (int r = 0; r < 4; r++) { fsv[r] += acc[nt4][r]*as; fdv[r] += acc[nt4][r]*ad; }
    }
    #pragma unroll
    for (int mask = 1; mask < 16; mask <<= 1) {
        #pragma unroll
        for (int r = 0; r < 4; r++) {
            fsv[r] += __shfl_xor(fsv[r], mask);
            fdv[r] += __shfl_xor(fdv[r], mask);
        }
    }
    if (lr == 0) {
        #pragma unroll
        for (int r = 0; r < 4; r++) {
            atomicAdd(&fs_l[lg*4 + r], fsv[r]);
            atomicAdd(&fd_l[lg*4 + r], fdv[r]);
        }
    }
    __syncthreads();
    if (threadIdx.x < 16) {
        float fsu = fs_l[threadIdx.x] * LOG2E;
        float fdu = fd_l[threadIdx.x] * LOG2E;
        fs2[b*NN + ib + threadIdx.x] = fsu;
        fd2[b*NN + ib + threadIdx.x] = fdu;
        float wm = fdu;
        #pragma unroll
        for (int m = 1; m < 16; m <<= 1) wm = fmaxf(wm, __shfl_xor(wm, m));
        if (threadIdx.x == 0) atomicMax(maxfd + b, enc_ord(wm));
    }
}

// ---- fused: masked softmax + att@h + elu — PURE DATAFLOW main loop ----
// grid 512 = 4b x 64 itile(32 rows) x 2 fh(128 f); 256 thr = 4 kt waves.
// NO barriers / NO LDS in the loop. B-frags: 8 coalesced 1KB wave-loads/step
// from hTs (swizzled by h_kernel). adj read directly (HBM stream, depth-3
// register prefetch); B depth-2; full unroll -> static reg rotation.
// Row sums via ones-B MFMA. Epilogue: kt-tree in LDS.
__global__ __launch_bounds__(256,2) void gat_fused(
    const short* __restrict__ hTs, const int* __restrict__ adj,
    const float* __restrict__ fs2, const float* __restrict__ fd2,
    const unsigned* __restrict__ maxfd, float* __restrict__ out)
{
    __shared__ float red[2][32*132];             // epilogue only (~34 KB)

    const int tid = threadIdx.x;
    const int kt = tid >> 6, l = tid & 63, lr = l & 15, lg = l >> 4;
    const int blk = blockIdx.x;
    const int b = blk >> 7, rest = blk & 127;
    const int itile = rest >> 1, fh = rest & 1;
    const int i0 = itile * 32, f0 = fh * 128;

    // per-row softmax constants (rows i0+lr and i0+16+lr), log2-scaled
    const float mx2 = dec_ord(maxfd[b]);
    const int gi0 = b*NN + i0 + lr;
    const float fsa = fs2[gi0], fsb = fs2[gi0 + 16];
    const float M0 = fmaxf(fsa + mx2, 0.f), M1 = fmaxf(fsb + mx2, 0.f);
    const float fsM0 = fsa - M0, nM0 = -M0;
    const float fsM1 = fsb - M1, nM1 = -M1;

    const int* ar0 = adj + (size_t)gi0 * NN + kt*32 + lg*8;
    const int* ar1 = ar0 + (size_t)16 * NN;
    const float* fdp = fd2 + b*NN + kt*32 + lg*8;
    const short* bbase = hTs + (((size_t)(b*2 + fh)*16)*4 + kt)*4096 + l*8;

    f32x4 acc[2][8];
    #pragma unroll
    for (int i = 0; i < 2; ++i)
        #pragma unroll
        for (int j = 0; j < 8; ++j) acc[i][j] = (f32x4){0.f,0.f,0.f,0.f};
    f32x4 acc1[2];
    acc1[0] = (f32x4){0.f,0.f,0.f,0.f};
    acc1[1] = (f32x4){0.f,0.f,0.f,0.f};

    bf16x8 bONE;
    #pragma unroll
    for (int d = 0; d < 8; ++d) bONE[d] = (short)0x3F80;   // bf16 1.0

    bf16x8 Bv[2][8];                             // depth-2 B prefetch
    int4   ja[3][4];                             // depth-3 adj prefetch
    f32x4  jf[3][2];                             // depth-3 fd prefetch

    auto LOADB = [&](int t, int s) {
        const short* p = bbase + (size_t)t * 16384;
        #pragma unroll
        for (int nt = 0; nt < 8; ++nt)
            Bv[s][nt] = *(const bf16x8*)(p + nt*512);
    };
    auto LOADA = [&](int t, int s) {
        const int base = t << 7;
        ja[s][0] = *(const int4*)(ar0 + base);
        ja[s][1] = *(const int4*)(ar0 + base + 4);
        ja[s][2] = *(const int4*)(ar1 + base);
        ja[s][3] = *(const int4*)(ar1 + base + 4);
        jf[s][0] = *(const f32x4*)(fdp + base);
        jf[s][1] = *(const f32x4*)(fdp + base + 4);
    };
    auto BODY = [&](int bs, int as) {
        const float fdv[8] = {jf[as][0][0], jf[as][0][1], jf[as][0][2], jf[as][0][3],
                              jf[as][1][0], jf[as][1][1], jf[as][1][2], jf[as][1][3]};
        const int a0v[8] = {ja[as][0].x, ja[as][0].y, ja[as][0].z, ja[as][0].w,
                            ja[as][1].x, ja[as][1].y, ja[as][1].z, ja[as][1].w};
        const int a1v[8] = {ja[as][2].x, ja[as][2].y, ja[as][2].z, ja[as][2].w,
                            ja[as][3].x, ja[as][3].y, ja[as][3].z, ja[as][3].w};
        float p0[8], p1[8];
        #pragma unroll
        for (int e = 0; e < 8; ++e) {
            float v0 = __builtin_amdgcn_exp2f(fmaxf(fsM0 + fdv[e], nM0));
            float v1 = __builtin_amdgcn_exp2f(fmaxf(fsM1 + fdv[e], nM1));
            p0[e] = (a0v[e] > 0) ? v0 : 0.f;
            p1[e] = (a1v[e] > 0) ? v1 : 0.f;
        }
        union { bf16x8 v; unsigned u[4]; } a0u, a1u;
        #pragma unroll
        for (int d = 0; d < 4; ++d) {
            asm("v_cvt_pk_bf16_f32 %0, %1, %2" : "=v"(a0u.u[d]) : "v"(p0[2*d]), "v"(p0[2*d+1]));
            asm("v_cvt_pk_bf16_f32 %0, %1, %2" : "=v"(a1u.u[d]) : "v"(p1[2*d]), "v"(p1[2*d+1]));
        }
        #pragma unroll
        for (int nt = 0; nt < 8; ++nt) {
            acc[0][nt] = __builtin_amdgcn_mfma_f32_16x16x32_bf16(a0u.v, Bv[bs][nt], acc[0][nt], 0, 0, 0);
            acc[1][nt] = __builtin_amdgcn_mfma_f32_16x16x32_bf16(a1u.v, Bv[bs][nt], acc[1][nt], 0, 0, 0);
        }
        acc1[0] = __builtin_amdgcn_mfma_f32_16x16x32_bf16(a0u.v, bONE, acc1[0], 0, 0, 0);
        acc1[1] = __builtin_amdgcn_mfma_f32_16x16x32_bf16(a1u.v, bONE, acc1[1], 0, 0, 0);
    };

    // prologue
    LOADA(0, 0);
    LOADA(1, 1);
    LOADB(0, 0);

    #pragma unroll
    for (int t = 0; t < 16; ++t) {
        if (t + 2 < 16) LOADA(t + 2, (t + 2) % 3);
        if (t + 1 < 16) LOADB(t + 1, (t + 1) & 1);
        BODY(t & 1, t % 3);
    }

    // ---- epilogue: kt-tree reduction (rowsums at col 128) + elu + store ----
    __syncthreads();
    float* r0 = red[0];
    float* r1 = red[1];
    if (kt >= 2) {
        float* dst = (kt == 2) ? r0 : r1;
        #pragma unroll
        for (int mt = 0; mt < 2; ++mt) {
            #pragma unroll
            for (int nt = 0; nt < 8; ++nt)
                #pragma unroll
                for (int r = 0; r < 4; ++r)
                    dst[(mt*16 + lg*4 + r)*132 + nt*16 + lr] = acc[mt][nt][r];
            if (lr == 0)
                #pragma unroll
                for (int r = 0; r < 4; ++r)
                    dst[(mt*16 + lg*4 + r)*132 + 128] = acc1[mt][r];
        }
    }
    __syncthreads();
    if (kt < 2) {
        const float* srcp = (kt == 0) ? r0 : r1;
        #pragma unroll
        for (int mt = 0; mt < 2; ++mt) {
            #pragma unroll
            for (int nt = 0; nt < 8; ++nt)
                #pragma unroll
                for (int r = 0; r < 4; ++r)
                    acc[mt][nt][r] += srcp[(mt*16 + lg*4 + r)*132 + nt*16 + lr];
            #pragma unroll
            for (int r = 0; r < 4; ++r)
                acc1[mt][r] += srcp[(mt*16 + lg*4 + r)*132 + 128];
        }
    }
    __syncthreads();
    if (kt == 1) {
        #pragma unroll
        for (int mt = 0; mt < 2; ++mt) {
            #pragma unroll
            for (int nt = 0; nt < 8; ++nt)
                #pragma unroll
                for (int r = 0; r < 4; ++r)
                    r0[(mt*16 + lg*4 + r)*132 + nt*16 + lr] = acc[mt][nt][r];
            if (lr == 0)
                #pragma unroll
                for (int r = 0; r < 4; ++r)
                    r0[(mt*16 + lg*4 + r)*132 + 128] = acc1[mt][r];
        }
    }
    __syncthreads();
    if (kt == 0) {
        #pragma unroll
        for (int mt = 0; mt < 2; ++mt) {
            float rv[4];
            #pragma unroll
            for (int r = 0; r < 4; ++r) {
                float tot = acc1[mt][r] + r0[(mt*16 + lg*4 + r)*132 + 128];
                rv[r] = tot > 0.f ? 1.f / tot : 0.f;
            }
            #pragma unroll
            for (int nt = 0; nt < 8; ++nt)
                #pragma unroll
                for (int r = 0; r < 4; ++r) {
                    float v = acc[mt][nt][r]
                            + r0[(mt*16 + lg*4 + r)*132 + nt*16 + lr];
                    v *= rv[r];
                    v = v > 0.f ? v : expm1f(v);
                    int row = i0 + mt*16 + lg*4 + r;
                    out[(size_t)(b*NN + row)*NF + f0 + nt*16 + lr] = v;
                }
        }
    }
}

extern "C" void kernel_launch(void* const* d_in, const int* in_sizes, int n_in,
                              void* d_out, int out_size, void* d_ws, size_t ws_size,
                              hipStream_t stream) {
    const float* x   = (const float*)d_in[0];
    const int*   adj = (const int*)d_in[1];
    const float* W   = (const float*)d_in[2];
    const float* a   = (const float*)d_in[3];
    float* out = (float*)d_out;
    char* ws = (char*)d_ws;

    short* WT       = (short*)(ws);                   // 128 KB
    short* hTs      = (short*)(ws + 0x20000);         // 4 MB (swizzled)
    float* fs2      = (float*)(ws + 0x420000);        // 32 KB
    float* fd2      = (float*)(ws + 0x428000);        // 32 KB
    unsigned* maxfd = (unsigned*)(ws + 0x430000);     // 16 B

    prep_kernel<<<(NF*NF)/256 + 1, 256, 0, stream>>>(W, WT, maxfd);
    h_kernel<<<(NB*NN)/16, 256, 0, stream>>>(x, WT, a, hTs, fs2, fd2, maxfd);
    gat_fused<<<NB*128, 256, 0, stream>>>(hTs, adj, fs2, fd2, maxfd, out);
}

// Round 13
// 63.496 us; speedup vs baseline: 1.3691x; 1.3691x over previous
//
#include <hip/hip_runtime.h>
#include <hip/hip_bf16.h>

#define NB 4
#define NN 2048
#define NF 256
#define LOG2E 1.4426950408889634f

using bf16x8 = __attribute__((ext_vector_type(8))) short;
using f32x4  = __attribute__((ext_vector_type(4))) float;

__device__ __forceinline__ short f2bf(float f) {
    unsigned u = __float_as_uint(f);
    u += 0x7fffu + ((u >> 16) & 1u);   // RNE, finite inputs only
    return (short)(u >> 16);
}
__device__ __forceinline__ unsigned enc_ord(float f) {
    unsigned u = __float_as_uint(f);
    return (u & 0x80000000u) ? ~u : (u | 0x80000000u);
}
__device__ __forceinline__ float dec_ord(unsigned u) {
    unsigned i = (u & 0x80000000u) ? (u & 0x7fffffffu) : ~u;
    return __uint_as_float(i);
}
__device__ __forceinline__ void gll16(const void* g, void* l) {
    __builtin_amdgcn_global_load_lds(
        (const __attribute__((address_space(1))) unsigned int*)g,
        (__attribute__((address_space(3))) unsigned int*)l, 16, 0, 0);
}

// ---- pack: adj -> 1-bit mask (R7-proven), W->W^T bf16, maxfd init ----
__global__ __launch_bounds__(256) void pack_kernel(
    const int* __restrict__ adj, unsigned short* __restrict__ adjB16,
    const float* __restrict__ W, short* __restrict__ WT, unsigned* __restrict__ maxfd)
{
    const int blk = blockIdx.x, tid = threadIdx.x;
    if (blk < 4096) {                       // 1M threads x 16 ints (64 B each)
        const int g = blk*256 + tid;
        const int4* p = (const int4*)(adj + (size_t)g*16);
        int4 v0 = p[0], v1 = p[1], v2 = p[2], v3 = p[3];
        unsigned m = 0;
        m |= (v0.x>0)<<0;  m |= (v0.y>0)<<1;  m |= (v0.z>0)<<2;  m |= (v0.w>0)<<3;
        m |= (v1.x>0)<<4;  m |= (v1.y>0)<<5;  m |= (v1.z>0)<<6;  m |= (v1.w>0)<<7;
        m |= (v2.x>0)<<8;  m |= (v2.y>0)<<9;  m |= (v2.z>0)<<10; m |= (v2.w>0)<<11;
        m |= (v3.x>0)<<12; m |= (v3.y>0)<<13; m |= (v3.z>0)<<14; m |= (v3.w>0)<<15;
        adjB16[g] = (unsigned short)m;
    } else if (blk < 4096 + (NF*NF)/256) {
        int t = (blk - 4096)*256 + tid;
        WT[t] = f2bf(W[(t & 255)*NF + (t >> 8)]);   // WT[g][f] = W[f][g]
    } else if (tid < NB) {
        maxfd[tid] = 0u;
    }
}

// ---- h = x@W (bf16 MFMA, K-pipelined); hT[b][g][i], fs2/fd2 (x LOG2E), maxfd ----
__global__ __launch_bounds__(256,4) void h_kernel(
    const float* __restrict__ x, const short* __restrict__ WT, const float* __restrict__ a,
    short* __restrict__ hT, float* __restrict__ fs2, float* __restrict__ fd2,
    unsigned* __restrict__ maxfd)
{
    __shared__ float fs_l[16], fd_l[16];
    const int w  = threadIdx.x >> 6;
    const int l  = threadIdx.x & 63;
    const int lr = l & 15, lg = l >> 4;
    const int b  = blockIdx.x >> 7;
    const int ib = (blockIdx.x & 127) * 16;

    if (threadIdx.x < 16) { fs_l[threadIdx.x] = 0.f; fd_l[threadIdx.x] = 0.f; }
    __syncthreads();

    f32x4 acc[4];
    #pragma unroll
    for (int t = 0; t < 4; t++) acc[t] = (f32x4){0.f,0.f,0.f,0.f};

    const float* xrow = x + (size_t)(b*NN + ib + lr) * NF + 8*lg;
    const short* wtp  = WT + (size_t)(w*64 + lr) * NF + 8*lg;

    float4 xa[2][2]; bf16x8 bfr[2][4];
    xa[0][0] = *(const float4*)(xrow);
    xa[0][1] = *(const float4*)(xrow + 4);
    #pragma unroll
    for (int nt = 0; nt < 4; nt++) bfr[0][nt] = *(const bf16x8*)(wtp + nt*16*NF);

    #pragma unroll
    for (int ks = 0; ks < 8; ks++) {
        const int cur = ks & 1;
        if (ks < 7) {
            const int nxt = cur ^ 1;
            xa[nxt][0] = *(const float4*)(xrow + (ks+1)*32);
            xa[nxt][1] = *(const float4*)(xrow + (ks+1)*32 + 4);
            #pragma unroll
            for (int nt = 0; nt < 4; nt++)
                bfr[nxt][nt] = *(const bf16x8*)(wtp + nt*16*NF + (ks+1)*32);
        }
        bf16x8 af;
        af[0]=f2bf(xa[cur][0].x); af[1]=f2bf(xa[cur][0].y);
        af[2]=f2bf(xa[cur][0].z); af[3]=f2bf(xa[cur][0].w);
        af[4]=f2bf(xa[cur][1].x); af[5]=f2bf(xa[cur][1].y);
        af[6]=f2bf(xa[cur][1].z); af[7]=f2bf(xa[cur][1].w);
        #pragma unroll
        for (int nt = 0; nt < 4; nt++)
            acc[nt] = __builtin_amdgcn_mfma_f32_16x16x32_bf16(af, bfr[cur][nt], acc[nt], 0, 0, 0);
    }

    float fsv[4] = {0,0,0,0}, fdv[4] = {0,0,0,0};
    #pragma unroll
    for (int nt = 0; nt < 4; nt++) {
        int g = w*64 + nt*16 + lr;
        float as = a[g], ad = a[NF + g];
        short4 hv;
        hv.x = f2bf(acc[nt][0]); hv.y = f2bf(acc[nt][1]);
        hv.z = f2bf(acc[nt][2]); hv.w = f2bf(acc[nt][3]);
        *(short4*)(hT + ((size_t)(b*NF + g))*NN + ib + lg*4) = hv;
        #pragma unroll
        for (int r = 0; r < 4; r++) { fsv[r] += acc[nt][r]*as; fdv[r] += acc[nt][r]*ad; }
    }
    #pragma unroll
    for (int mask = 1; mask < 16; mask <<= 1) {
        #pragma unroll
        for (int r = 0; r < 4; r++) {
            fsv[r] += __shfl_xor(fsv[r], mask);
            fdv[r] += __shfl_xor(fdv[r], mask);
        }
    }
    if (lr == 0) {
        #pragma unroll
        for (int r = 0; r < 4; r++) {
            atomicAdd(&fs_l[lg*4 + r], fsv[r]);
            atomicAdd(&fd_l[lg*4 + r], fdv[r]);
        }
    }
    __syncthreads();
    if (threadIdx.x < 16) {
        float fsu = fs_l[threadIdx.x] * LOG2E;
        float fdu = fd_l[threadIdx.x] * LOG2E;
        fs2[b*NN + ib + threadIdx.x] = fsu;
        fd2[b*NN + ib + threadIdx.x] = fdu;
        float wm = fdu;
        #pragma unroll
        for (int m = 1; m < 16; m <<= 1) wm = fmaxf(wm, __shfl_xor(wm, m));
        if (threadIdx.x == 0) atomicMax(maxfd + b, enc_ord(wm));
    }
}

// ---- fused: masked softmax + att@h + elu ----
// grid 512 = 4b x 64 itile(32 rows) x 2 fh(128 f); 512 thr = 8 waves
// = 2 rowg(16 rows) x 4 kt(32-j slice of BK=128); 2 blocks/CU -> 16 waves/CU.
// Exp once per (i,j) per fh (x2); adj via packed mask bytes (L2-resident).
// P in-register -> A-frag; B via 2x32KB LDS slots (XOR chunk swizzle);
// per-thread fence vmcnt(3) (STAGE=4 gll + LOADP=3 loads). Ones-MFMA rowsums.
__global__ __launch_bounds__(512,4) void gat_fused(
    const short* __restrict__ hT, const unsigned char* __restrict__ adjB,
    const float* __restrict__ fs2, const float* __restrict__ fd2,
    const unsigned* __restrict__ maxfd, float* __restrict__ out)
{
    __shared__ __align__(16) char smem[65536];   // 2 x 32KB staging (epilogue aliases)

    const int tid = threadIdx.x;
    const int w = tid >> 6, l = tid & 63, lr = l & 15, lg = l >> 4;
    const int kt = w & 3, rowg = w >> 2;
    const int blk = blockIdx.x;
    const int b = blk >> 7, rest = blk & 127;
    const int itile = rest >> 1, fh = rest & 1;
    const int i0 = itile * 32, f0 = fh * 128;

    const short* hTb = hT + ((size_t)b * NF + f0) * NN;

    // staging sources: 4 chunks/thread (2048 chunks = 32KB), inverse-XOR swizzle
    const short* sbp[4];
    #pragma unroll
    for (int i = 0; i < 4; ++i) {
        int s = tid + 512*i;
        int r = s >> 4, pc = s & 15;
        int c = pc ^ (r & 15);
        sbp[i] = hTb + (size_t)r * NN + c*8;
    }

    // this thread's P row: i0 + rowg*16 + lr, log2-scaled constants
    const float mx2 = dec_ord(maxfd[b]);
    const int gi = b*NN + i0 + rowg*16 + lr;
    const float fsv_ = fs2[gi];
    const float M = fmaxf(fsv_ + mx2, 0.f);
    const float fsM = fsv_ - M, nM = -M;

    const unsigned char* ar = adjB + (size_t)gi * (NN/8) + kt*4 + lg;
    const float* fdp = fd2 + b*NN + kt*32 + lg*8;

    const int boff = lr*256 + (((kt*4 + lg) ^ lr) << 4);   // + nt*4096 per f-tile

    f32x4 acc[8];
    #pragma unroll
    for (int j = 0; j < 8; ++j) acc[j] = (f32x4){0.f,0.f,0.f,0.f};
    f32x4 acc1 = (f32x4){0.f,0.f,0.f,0.f};

    bf16x8 bONE;
    #pragma unroll
    for (int d = 0; d < 8; ++d) bONE[d] = (short)0x3F80;   // bf16 1.0

    auto STAGE = [&](int t, int slot) {          // 4 gll/thread, 32KB tile
        char* dst = smem + slot * 32768;
        #pragma unroll
        for (int i = 0; i < 4; ++i)
            gll16(sbp[i] + t*128, dst + (tid + 512*i)*16);
    };
    auto LOADP = [&](int t, unsigned& m8, f32x4& fa, f32x4& fb) {
        m8 = ar[t*16];
        fa = *(const f32x4*)(fdp + (t << 7));
        fb = *(const f32x4*)(fdp + (t << 7) + 4);
    };
    auto BODY = [&](int slot, unsigned m8, const f32x4& fa, const f32x4& fb) {
        const char* sb = smem + slot * 32768;
        bf16x8 B[8];
        #pragma unroll
        for (int nt = 0; nt < 8; ++nt)
            B[nt] = *(const bf16x8*)(sb + boff + nt*4096);
        const float fdv[8] = {fa[0],fa[1],fa[2],fa[3],fb[0],fb[1],fb[2],fb[3]};
        float p[8];
        #pragma unroll
        for (int e = 0; e < 8; ++e) {
            float v = __builtin_amdgcn_exp2f(fmaxf(fsM + fdv[e], nM));
            p[e] = (m8 & (1u << e)) ? v : 0.f;
        }
        union { bf16x8 v; unsigned u[4]; } au;
        #pragma unroll
        for (int d = 0; d < 4; ++d)
            asm("v_cvt_pk_bf16_f32 %0, %1, %2" : "=v"(au.u[d]) : "v"(p[2*d]), "v"(p[2*d+1]));
        #pragma unroll
        for (int nt = 0; nt < 8; ++nt)
            acc[nt] = __builtin_amdgcn_mfma_f32_16x16x32_bf16(au.v, B[nt], acc[nt], 0, 0, 0);
        acc1 = __builtin_amdgcn_mfma_f32_16x16x32_bf16(au.v, bONE, acc1, 0, 0, 0);
    };
    #define FENCE3 do { __builtin_amdgcn_sched_barrier(0); \
        asm volatile("s_waitcnt vmcnt(3)" ::: "memory"); \
        __builtin_amdgcn_s_barrier(); \
        __builtin_amdgcn_sched_barrier(0); } while (0)
    #define FENCE0 do { __builtin_amdgcn_sched_barrier(0); \
        asm volatile("s_waitcnt vmcnt(0)" ::: "memory"); \
        __builtin_amdgcn_s_barrier(); \
        __builtin_amdgcn_sched_barrier(0); } while (0)

    unsigned mA, mB;
    f32x4 fAa, fAb, fBa, fBb;

    // prologue: S0 + P0 + P1; wait S0+P0 (leave P1's 3 in flight)
    STAGE(0, 0);
    LOADP(0, mA, fAa, fAb);
    LOADP(1, mB, fBa, fBb);
    FENCE3;

    for (int t2 = 0; t2 < 16; t2 += 2) {
        // even step t2 (set A, slot 0)
        STAGE(t2 + 1, 1);
        BODY(0, mA, fAa, fAb);
        if (t2 + 2 < 16) {
            LOADP(t2 + 2, mA, fAa, fAb);
            FENCE3;                          // waits S(t2+1)+P(t2+1); leaves P(t2+2)
        } else {
            FENCE0;                          // tail: drain STAGE(15)
        }
        // odd step t2+1 (set B, slot 1)
        if (t2 + 2 < 16) STAGE(t2 + 2, 0);
        BODY(1, mB, fBa, fBb);
        if (t2 + 3 < 16) {
            LOADP(t2 + 3, mB, fBa, fBb);
            FENCE3;                          // waits S(t2+2)+P(t2+2); leaves P(t2+3)
        }
    }
    __syncthreads();                         // loop done; LDS reused for reduction

    // ---- epilogue: kt-tree per rowg (rowsums at col 128) + elu + store ----
    float* red0 = (float*)smem;              // [2 rowg][16 rows][132]
    float* red1 = (float*)(smem + 16896);
    float* myr0 = red0 + rowg * 16*132;
    float* myr1 = red1 + rowg * 16*132;
    if (kt >= 2) {
        float* dst = (kt == 2) ? myr0 : myr1;
        #pragma unroll
        for (int nt = 0; nt < 8; ++nt)
            #pragma unroll
            for (int r = 0; r < 4; ++r)
                dst[(lg*4 + r)*132 + nt*16 + lr] = acc[nt][r];
        if (lr == 0)
            #pragma unroll
            for (int r = 0; r < 4; ++r)
                dst[(lg*4 + r)*132 + 128] = acc1[r];
    }
    __syncthreads();
    if (kt < 2) {
        const float* srcp = (kt == 0) ? myr0 : myr1;
        #pragma unroll
        for (int nt = 0; nt < 8; ++nt)
            #pragma unroll
            for (int r = 0; r < 4; ++r)
                acc[nt][r] += srcp[(lg*4 + r)*132 + nt*16 + lr];
        #pragma unroll
        for (int r = 0; r < 4; ++r)
            acc1[r] += srcp[(lg*4 + r)*132 + 128];
    }
    __syncthreads();
    if (kt == 1) {
        #pragma unroll
        for (int nt = 0; nt < 8; ++nt)
            #pragma unroll
            for (int r = 0; r < 4; ++r)
                myr0[(lg*4 + r)*132 + nt*16 + lr] = acc[nt][r];
        if (lr == 0)
            #pragma unroll
            for (int r = 0; r < 4; ++r)
                myr0[(lg*4 + r)*132 + 128] = acc1[r];
    }
    __syncthreads();
    if (kt == 0) {
        float rv[4];
        #pragma unroll
        for (int r = 0; r < 4; ++r) {
            float tot = acc1[r] + myr0[(lg*4 + r)*132 + 128];
            rv[r] = tot > 0.f ? 1.f / tot : 0.f;
        }
        #pragma unroll
        for (int nt = 0; nt < 8; ++nt)
            #pragma unroll
            for (int r = 0; r < 4; ++r) {
                float v = acc[nt][r] + myr0[(lg*4 + r)*132 + nt*16 + lr];
                v *= rv[r];
                v = v > 0.f ? v : expm1f(v);
                int row = i0 + rowg*16 + lg*4 + r;
                out[(size_t)(b*NN + row)*NF + f0 + nt*16 + lr] = v;
            }
    }
    #undef FENCE3
    #undef FENCE0
}

extern "C" void kernel_launch(void* const* d_in, const int* in_sizes, int n_in,
                              void* d_out, int out_size, void* d_ws, size_t ws_size,
                              hipStream_t stream) {
    const float* x   = (const float*)d_in[0];
    const int*   adj = (const int*)d_in[1];
    const float* W   = (const float*)d_in[2];
    const float* a   = (const float*)d_in[3];
    float* out = (float*)d_out;
    char* ws = (char*)d_ws;

    short* WT       = (short*)(ws);                   // 128 KB
    short* hT       = (short*)(ws + 0x20000);         // 4 MB
    float* fs2      = (float*)(ws + 0x420000);        // 32 KB
    float* fd2      = (float*)(ws + 0x428000);        // 32 KB
    unsigned* maxfd = (unsigned*)(ws + 0x430000);     // 16 B
    unsigned short* adjB16 = (unsigned short*)(ws + 0x440000); // 2 MB

    pack_kernel<<<4096 + (NF*NF)/256 + 1, 256, 0, stream>>>(adj, adjB16, W, WT, maxfd);
    h_kernel<<<(NB*NN)/16, 256, 0, stream>>>(x, WT, a, hT, fs2, fd2, maxfd);
    gat_fused<<<NB*128, 512, 0, stream>>>(hT, (const unsigned char*)adjB16,
                                          fs2, fd2, maxfd, out);
}

// Round 14
// 61.216 us; speedup vs baseline: 1.4201x; 1.0372x over previous
//
#include <hip/hip_runtime.h>
#include <hip/hip_bf16.h>

#define NB 4
#define NN 2048
#define NF 256
#define LOG2E 1.4426950408889634f

using bf16x8 = __attribute__((ext_vector_type(8))) short;
using f32x4  = __attribute__((ext_vector_type(4))) float;

__device__ __forceinline__ short f2bf(float f) {
    unsigned u = __float_as_uint(f);
    u += 0x7fffu + ((u >> 16) & 1u);   // RNE, finite inputs only
    return (short)(u >> 16);
}
__device__ __forceinline__ unsigned enc_ord(float f) {
    unsigned u = __float_as_uint(f);
    return (u & 0x80000000u) ? ~u : (u | 0x80000000u);
}
__device__ __forceinline__ float dec_ord(unsigned u) {
    unsigned i = (u & 0x80000000u) ? (u & 0x7fffffffu) : ~u;
    return __uint_as_float(i);
}
__device__ __forceinline__ void gll16(const void* g, void* l) {
    __builtin_amdgcn_global_load_lds(
        (const __attribute__((address_space(1))) unsigned int*)g,
        (__attribute__((address_space(3))) unsigned int*)l, 16, 0, 0);
}

// ---- prep: W->W^T bf16, maxfd init (tiny; must precede work2's h blocks) ----
__global__ __launch_bounds__(256) void prep_kernel(
    const float* __restrict__ W, short* __restrict__ WT, unsigned* __restrict__ maxfd)
{
    const int blk = blockIdx.x, tid = threadIdx.x;
    if (blk < (NF*NF)/256) {
        int t = blk*256 + tid;
        WT[t] = f2bf(W[(t & 255)*NF + (t >> 8)]);   // WT[g][f] = W[f][g]
    } else if (tid < NB) {
        maxfd[tid] = 0u;
    }
}

// ---- work2: blocks [0,512) = h GEMM (starts first, rides under pack's HBM
//      stream); blocks [512,4608) = adj->bitmask pack (64 B/thread) ----
__global__ __launch_bounds__(256,4) void work2_kernel(
    const int* __restrict__ adj, unsigned short* __restrict__ adjB16,
    const float* __restrict__ x, const short* __restrict__ WT, const float* __restrict__ a,
    short* __restrict__ hT, float* __restrict__ fs2, float* __restrict__ fd2,
    unsigned* __restrict__ maxfd)
{
    if (blockIdx.x >= 512) {                // pack: 1M threads x 16 ints
        const int g = (blockIdx.x - 512)*256 + threadIdx.x;
        const int4* p = (const int4*)(adj + (size_t)g*16);
        int4 v0 = p[0], v1 = p[1], v2 = p[2], v3 = p[3];
        unsigned m = 0;
        m |= (v0.x>0)<<0;  m |= (v0.y>0)<<1;  m |= (v0.z>0)<<2;  m |= (v0.w>0)<<3;
        m |= (v1.x>0)<<4;  m |= (v1.y>0)<<5;  m |= (v1.z>0)<<6;  m |= (v1.w>0)<<7;
        m |= (v2.x>0)<<8;  m |= (v2.y>0)<<9;  m |= (v2.z>0)<<10; m |= (v2.w>0)<<11;
        m |= (v3.x>0)<<12; m |= (v3.y>0)<<13; m |= (v3.z>0)<<14; m |= (v3.w>0)<<15;
        adjB16[g] = (unsigned short)m;
        return;
    }
    // ---- h = x@W (bf16 MFMA, K-pipelined) ----
    __shared__ float fs_l[16], fd_l[16];
    const int hb = blockIdx.x;
    const int w  = threadIdx.x >> 6;
    const int l  = threadIdx.x & 63;
    const int lr = l & 15, lg = l >> 4;
    const int b  = hb >> 7;
    const int ib = (hb & 127) * 16;

    if (threadIdx.x < 16) { fs_l[threadIdx.x] = 0.f; fd_l[threadIdx.x] = 0.f; }
    __syncthreads();

    f32x4 acc[4];
    #pragma unroll
    for (int t = 0; t < 4; t++) acc[t] = (f32x4){0.f,0.f,0.f,0.f};

    const float* xrow = x + (size_t)(b*NN + ib + lr) * NF + 8*lg;
    const short* wtp  = WT + (size_t)(w*64 + lr) * NF + 8*lg;

    float4 xa[2][2]; bf16x8 bfr[2][4];
    xa[0][0] = *(const float4*)(xrow);
    xa[0][1] = *(const float4*)(xrow + 4);
    #pragma unroll
    for (int nt = 0; nt < 4; nt++) bfr[0][nt] = *(const bf16x8*)(wtp + nt*16*NF);

    #pragma unroll
    for (int ks = 0; ks < 8; ks++) {
        const int cur = ks & 1;
        if (ks < 7) {
            const int nxt = cur ^ 1;
            xa[nxt][0] = *(const float4*)(xrow + (ks+1)*32);
            xa[nxt][1] = *(const float4*)(xrow + (ks+1)*32 + 4);
            #pragma unroll
            for (int nt = 0; nt < 4; nt++)
                bfr[nxt][nt] = *(const bf16x8*)(wtp + nt*16*NF + (ks+1)*32);
        }
        bf16x8 af;
        af[0]=f2bf(xa[cur][0].x); af[1]=f2bf(xa[cur][0].y);
        af[2]=f2bf(xa[cur][0].z); af[3]=f2bf(xa[cur][0].w);
        af[4]=f2bf(xa[cur][1].x); af[5]=f2bf(xa[cur][1].y);
        af[6]=f2bf(xa[cur][1].z); af[7]=f2bf(xa[cur][1].w);
        #pragma unroll
        for (int nt = 0; nt < 4; nt++)
            acc[nt] = __builtin_amdgcn_mfma_f32_16x16x32_bf16(af, bfr[cur][nt], acc[nt], 0, 0, 0);
    }

    float fsv[4] = {0,0,0,0}, fdv[4] = {0,0,0,0};
    #pragma unroll
    for (int nt = 0; nt < 4; nt++) {
        int g = w*64 + nt*16 + lr;
        float as = a[g], ad = a[NF + g];
        short4 hv;
        hv.x = f2bf(acc[nt][0]); hv.y = f2bf(acc[nt][1]);
        hv.z = f2bf(acc[nt][2]); hv.w = f2bf(acc[nt][3]);
        *(short4*)(hT + ((size_t)(b*NF + g))*NN + ib + lg*4) = hv;
        #pragma unroll
        for (int r = 0; r < 4; r++) { fsv[r] += acc[nt][r]*as; fdv[r] += acc[nt][r]*ad; }
    }
    #pragma unroll
    for (int mask = 1; mask < 16; mask <<= 1) {
        #pragma unroll
        for (int r = 0; r < 4; r++) {
            fsv[r] += __shfl_xor(fsv[r], mask);
            fdv[r] += __shfl_xor(fdv[r], mask);
        }
    }
    if (lr == 0) {
        #pragma unroll
        for (int r = 0; r < 4; r++) {
            atomicAdd(&fs_l[lg*4 + r], fsv[r]);
            atomicAdd(&fd_l[lg*4 + r], fdv[r]);
        }
    }
    __syncthreads();
    if (threadIdx.x < 16) {
        float fsu = fs_l[threadIdx.x] * LOG2E;
        float fdu = fd_l[threadIdx.x] * LOG2E;
        fs2[b*NN + ib + threadIdx.x] = fsu;
        fd2[b*NN + ib + threadIdx.x] = fdu;
        float wm = fdu;
        #pragma unroll
        for (int m = 1; m < 16; m <<= 1) wm = fmaxf(wm, __shfl_xor(wm, m));
        if (threadIdx.x == 0) atomicMax(maxfd + b, enc_ord(wm));
    }
}

// ---- fused: masked softmax + att@h + elu (UNCHANGED from R13) ----
// grid 512 = 4b x 64 itile(32 rows) x 2 fh(128 f); 512 thr = 8 waves
// = 2 rowg(16 rows) x 4 kt(32-j slice of BK=128); 2 blocks/CU -> 16 waves/CU.
__global__ __launch_bounds__(512,4) void gat_fused(
    const short* __restrict__ hT, const unsigned char* __restrict__ adjB,
    const float* __restrict__ fs2, const float* __restrict__ fd2,
    const unsigned* __restrict__ maxfd, float* __restrict__ out)
{
    __shared__ __align__(16) char smem[65536];   // 2 x 32KB staging (epilogue aliases)

    const int tid = threadIdx.x;
    const int w = tid >> 6, l = tid & 63, lr = l & 15, lg = l >> 4;
    const int kt = w & 3, rowg = w >> 2;
    const int blk = blockIdx.x;
    const int b = blk >> 7, rest = blk & 127;
    const int itile = rest >> 1, fh = rest & 1;
    const int i0 = itile * 32, f0 = fh * 128;

    const short* hTb = hT + ((size_t)b * NF + f0) * NN;

    // staging sources: 4 chunks/thread (2048 chunks = 32KB), inverse-XOR swizzle
    const short* sbp[4];
    #pragma unroll
    for (int i = 0; i < 4; ++i) {
        int s = tid + 512*i;
        int r = s >> 4, pc = s & 15;
        int c = pc ^ (r & 15);
        sbp[i] = hTb + (size_t)r * NN + c*8;
    }

    // this thread's P row: i0 + rowg*16 + lr, log2-scaled constants
    const float mx2 = dec_ord(maxfd[b]);
    const int gi = b*NN + i0 + rowg*16 + lr;
    const float fsv_ = fs2[gi];
    const float M = fmaxf(fsv_ + mx2, 0.f);
    const float fsM = fsv_ - M, nM = -M;

    const unsigned char* ar = adjB + (size_t)gi * (NN/8) + kt*4 + lg;
    const float* fdp = fd2 + b*NN + kt*32 + lg*8;

    const int boff = lr*256 + (((kt*4 + lg) ^ lr) << 4);   // + nt*4096 per f-tile

    f32x4 acc[8];
    #pragma unroll
    for (int j = 0; j < 8; ++j) acc[j] = (f32x4){0.f,0.f,0.f,0.f};
    f32x4 acc1 = (f32x4){0.f,0.f,0.f,0.f};

    bf16x8 bONE;
    #pragma unroll
    for (int d = 0; d < 8; ++d) bONE[d] = (short)0x3F80;   // bf16 1.0

    auto STAGE = [&](int t, int slot) {          // 4 gll/thread, 32KB tile
        char* dst = smem + slot * 32768;
        #pragma unroll
        for (int i = 0; i < 4; ++i)
            gll16(sbp[i] + t*128, dst + (tid + 512*i)*16);
    };
    auto LOADP = [&](int t, unsigned& m8, f32x4& fa, f32x4& fb) {
        m8 = ar[t*16];
        fa = *(const f32x4*)(fdp + (t << 7));
        fb = *(const f32x4*)(fdp + (t << 7) + 4);
    };
    auto BODY = [&](int slot, unsigned m8, const f32x4& fa, const f32x4& fb) {
        const char* sb = smem + slot * 32768;
        bf16x8 B[8];
        #pragma unroll
        for (int nt = 0; nt < 8; ++nt)
            B[nt] = *(const bf16x8*)(sb + boff + nt*4096);
        const float fdv[8] = {fa[0],fa[1],fa[2],fa[3],fb[0],fb[1],fb[2],fb[3]};
        float p[8];
        #pragma unroll
        for (int e = 0; e < 8; ++e) {
            float v = __builtin_amdgcn_exp2f(fmaxf(fsM + fdv[e], nM));
            p[e] = (m8 & (1u << e)) ? v : 0.f;
        }
        union { bf16x8 v; unsigned u[4]; } au;
        #pragma unroll
        for (int d = 0; d < 4; ++d)
            asm("v_cvt_pk_bf16_f32 %0, %1, %2" : "=v"(au.u[d]) : "v"(p[2*d]), "v"(p[2*d+1]));
        #pragma unroll
        for (int nt = 0; nt < 8; ++nt)
            acc[nt] = __builtin_amdgcn_mfma_f32_16x16x32_bf16(au.v, B[nt], acc[nt], 0, 0, 0);
        acc1 = __builtin_amdgcn_mfma_f32_16x16x32_bf16(au.v, bONE, acc1, 0, 0, 0);
    };
    #define FENCE3 do { __builtin_amdgcn_sched_barrier(0); \
        asm volatile("s_waitcnt vmcnt(3)" ::: "memory"); \
        __builtin_amdgcn_s_barrier(); \
        __builtin_amdgcn_sched_barrier(0); } while (0)
    #define FENCE0 do { __builtin_amdgcn_sched_barrier(0); \
        asm volatile("s_waitcnt vmcnt(0)" ::: "memory"); \
        __builtin_amdgcn_s_barrier(); \
        __builtin_amdgcn_sched_barrier(0); } while (0)

    unsigned mA, mB;
    f32x4 fAa, fAb, fBa, fBb;

    // prologue: S0 + P0 + P1; wait S0+P0 (leave P1's 3 in flight)
    STAGE(0, 0);
    LOADP(0, mA, fAa, fAb);
    LOADP(1, mB, fBa, fBb);
    FENCE3;

    for (int t2 = 0; t2 < 16; t2 += 2) {
        // even step t2 (set A, slot 0)
        STAGE(t2 + 1, 1);
        BODY(0, mA, fAa, fAb);
        if (t2 + 2 < 16) {
            LOADP(t2 + 2, mA, fAa, fAb);
            FENCE3;                          // waits S(t2+1)+P(t2+1); leaves P(t2+2)
        } else {
            FENCE0;                          // tail: drain STAGE(15)
        }
        // odd step t2+1 (set B, slot 1)
        if (t2 + 2 < 16) STAGE(t2 + 2, 0);
        BODY(1, mB, fBa, fBb);
        if (t2 + 3 < 16) {
            LOADP(t2 + 3, mB, fBa, fBb);
            FENCE3;                          // waits S(t2+2)+P(t2+2); leaves P(t2+3)
        }
    }
    __syncthreads();                         // loop done; LDS reused for reduction

    // ---- epilogue: kt-tree per rowg (rowsums at col 128) + elu + store ----
    float* red0 = (float*)smem;              // [2 rowg][16 rows][132]
    float* red1 = (float*)(smem + 16896);
    float* myr0 = red0 + rowg * 16*132;
    float* myr1 = red1 + rowg * 16*132;
    if (kt >= 2) {
        float* dst = (kt == 2) ? myr0 : myr1;
        #pragma unroll
        for (int nt = 0; nt < 8; ++nt)
            #pragma unroll
            for (int r = 0; r < 4; ++r)
                dst[(lg*4 + r)*132 + nt*16 + lr] = acc[nt][r];
        if (lr == 0)
            #pragma unroll
            for (int r = 0; r < 4; ++r)
                dst[(lg*4 + r)*132 + 128] = acc1[r];
    }
    __syncthreads();
    if (kt < 2) {
        const float* srcp = (kt == 0) ? myr0 : myr1;
        #pragma unroll
        for (int nt = 0; nt < 8; ++nt)
            #pragma unroll
            for (int r = 0; r < 4; ++r)
                acc[nt][r] += srcp[(lg*4 + r)*132 + nt*16 + lr];
        #pragma unroll
        for (int r = 0; r < 4; ++r)
            acc1[r] += srcp[(lg*4 + r)*132 + 128];
    }
    __syncthreads();
    if (kt == 1) {
        #pragma unroll
        for (int nt = 0; nt < 8; ++nt)
            #pragma unroll
            for (int r = 0; r < 4; ++r)
                myr0[(lg*4 + r)*132 + nt*16 + lr] = acc[nt][r];
        if (lr == 0)
            #pragma unroll
            for (int r = 0; r < 4; ++r)
                myr0[(lg*4 + r)*132 + 128] = acc1[r];
    }
    __syncthreads();
    if (kt == 0) {
        float rv[4];
        #pragma unroll
        for (int r = 0; r < 4; ++r) {
            float tot = acc1[r] + myr0[(lg*4 + r)*132 + 128];
            rv[r] = tot > 0.f ? 1.f / tot : 0.f;
        }
        #pragma unroll
        for (int nt = 0; nt < 8; ++nt)
            #pragma unroll
            for (int r = 0; r < 4; ++r) {
                float v = acc[nt][r] + myr0[(lg*4 + r)*132 + nt*16 + lr];
                v *= rv[r];
                v = v > 0.f ? v : expm1f(v);
                int row = i0 + rowg*16 + lg*4 + r;
                out[(size_t)(b*NN + row)*NF + f0 + nt*16 + lr] = v;
            }
    }
    #undef FENCE3
    #undef FENCE0
}

extern "C" void kernel_launch(void* const* d_in, const int* in_sizes, int n_in,
                              void* d_out, int out_size, void* d_ws, size_t ws_size,
                              hipStream_t stream) {
    const float* x   = (const float*)d_in[0];
    const int*   adj = (const int*)d_in[1];
    const float* W   = (const float*)d_in[2];
    const float* a   = (const float*)d_in[3];
    float* out = (float*)d_out;
    char* ws = (char*)d_ws;

    short* WT       = (short*)(ws);                   // 128 KB
    short* hT       = (short*)(ws + 0x20000);         // 4 MB
    float* fs2      = (float*)(ws + 0x420000);        // 32 KB
    float* fd2      = (float*)(ws + 0x428000);        // 32 KB
    unsigned* maxfd = (unsigned*)(ws + 0x430000);     // 16 B
    unsigned short* adjB16 = (unsigned short*)(ws + 0x440000); // 2 MB

    prep_kernel<<<(NF*NF)/256 + 1, 256, 0, stream>>>(W, WT, maxfd);
    work2_kernel<<<4608, 256, 0, stream>>>(adj, adjB16, x, WT, a,
                                           hT, fs2, fd2, maxfd);
    gat_fused<<<NB*128, 512, 0, stream>>>(hT, (const unsigned char*)adjB16,
                                          fs2, fd2, maxfd, out);
}